// Round 3
// baseline (118.087 us; speedup 1.0000x reference)
//
#include <hip/hip_runtime.h>

typedef __attribute__((ext_vector_type(4))) float  f32x4;
typedef __attribute__((ext_vector_type(8))) __bf16 bf16x8;
typedef __attribute__((ext_vector_type(4))) __bf16 bf16x4;

#define MFMA16(a, b, c) __builtin_amdgcn_mfma_f32_16x16x32_bf16((a), (b), (c), 0, 0, 0)

// 4 (b,h) problems per 1024-thread block: bs=2048, h=8, dh=32, qsl=sl=64.
// grid = 4096 blocks (16x fewer dispatches). LDS 59.4 KB -> 2 blocks/CU = 32 waves/CU.
__global__ __launch_bounds__(1024, 2)
void mha_fused(const float* __restrict__ qg, const float* __restrict__ kg,
               const float* __restrict__ vg, const unsigned char* __restrict__ maskg,
               const float* __restrict__ gammag, const float* __restrict__ biasg,
               float* __restrict__ outg)
{
    // XCD-bijective remap: the 2 blocks sharing one b (mask reuse) stay on one XCD.
    const int bid   = blockIdx.x;
    const int chunk = gridDim.x >> 3;              // 512
    const int vbid  = (bid & 7) * chunk + (bid >> 3);
    const int b  = vbid >> 1;
    const int hg = vbid & 1;

    const int t  = threadIdx.x;
    const int sb = t >> 8;          // sub-block 0..3 (one (b,h) each, 4 waves)
    const int lt = t & 255;
    const int h  = hg * 4 + sb;
    const int bh = b * 8 + h;

    // K^T split-bf16 [j][d], stride 40 bf16 = 80 B; 16B slots XOR-swizzled.
    __shared__ __bf16 sKh[4][64][40];
    __shared__ __bf16 sKl[4][64][40];
    __shared__ __bf16 sV [4][32][72];   // V bf16 [d][j], stride 144 B

    const float* qb = qg + (size_t)bh * 2048;
    const float* kb = kg + (size_t)bh * 2048;
    const float* vb = vg + (size_t)bh * 2048;
    const unsigned char* mb = maskg + (size_t)b * 4096;  // mask broadcast over h
    float* ob = outg + (size_t)bh * 2048;

    const int w  = (lt >> 6) & 3;   // wave within sub-block: query cols i = w*16..+15
    const int li = lt & 15;
    const int hi = (lt >> 4) & 3;
    const int i  = w * 16 + li;

    // ---- early: Q fragment direct from global (no cross-wave reuse) ----
    float qv[8];
    #pragma unroll
    for (int e = 0; e < 8; ++e) qv[e] = qb[(hi * 8 + e) * 64 + i];
    // ---- early: mask words (read-once, L2-resident across the 8 h's) ----
    unsigned int mw[4];
    #pragma unroll
    for (int jt = 0; jt < 4; ++jt)
        mw[jt] = *(const unsigned int*)&mb[i * 64 + jt * 16 + hi * 4];

    // ---- stage K^T split-bf16, one 16B slot per thread, XOR slot swizzle ----
    {
        const int j = lt & 63, sel = lt >> 6;
        float a[8];
        #pragma unroll
        for (int e = 0; e < 8; ++e) a[e] = kb[(sel * 8 + e) * 64 + j];
        bf16x8 h8, l8;
        #pragma unroll
        for (int e = 0; e < 8; ++e) {
            __bf16 hh = (__bf16)a[e];
            h8[e] = hh;
            l8[e] = (__bf16)(a[e] - (float)hh);
        }
        const int slot = sel ^ ((j >> 3) & 3);
        *(bf16x8*)&sKh[sb][j][slot * 8] = h8;
        *(bf16x8*)&sKl[sb][j][slot * 8] = l8;
    }
    // ---- stage V as bf16, natural [d][j] ----
    {
        const int d = lt >> 3, j0 = (lt & 7) * 8;
        f32x4 x0 = *(const f32x4*)&vb[d * 64 + j0];
        f32x4 x1 = *(const f32x4*)&vb[d * 64 + j0 + 4];
        bf16x8 vv = {(__bf16)x0[0], (__bf16)x0[1], (__bf16)x0[2], (__bf16)x0[3],
                     (__bf16)x1[0], (__bf16)x1[1], (__bf16)x1[2], (__bf16)x1[3]};
        *(bf16x8*)&sV[sb][d][j0] = vv;
    }

    // ---- Q split to hi+lo bf16 in registers ----
    bf16x8 qh, ql;
    #pragma unroll
    for (int e = 0; e < 8; ++e) {
        __bf16 hh = (__bf16)qv[e];
        qh[e] = hh;
        ql[e] = (__bf16)(qv[e] - (float)hh);
    }

    __syncthreads();

    // ---- S^T[j][i] = sum_d K^T[j][d] * Q[d][i] (split-bf16, 3 MFMAs/tile) ----
    const float ga = gammag[h], be = biasg[h];
    float s[16];
    #pragma unroll
    for (int jt = 0; jt < 4; ++jt) {
        const int j = jt * 16 + li;
        const int slot = hi ^ ((j >> 3) & 3);
        bf16x8 ah = *(bf16x8*)&sKh[sb][j][slot * 8];
        bf16x8 al = *(bf16x8*)&sKl[sb][j][slot * 8];
        f32x4 c = {0.f, 0.f, 0.f, 0.f};
        c = MFMA16(al, qh, c);   // lo*hi
        c = MFMA16(ah, ql, c);   // hi*lo
        c = MFMA16(ah, qh, c);   // hi*hi
        #pragma unroll
        for (int r = 0; r < 4; ++r) {
            float x = c[r] * ga + be;
            if ((mw[jt] >> (8 * r)) & 0xffu) x = -1.0e9f;
            s[jt * 4 + r] = x;
        }
    }

    // ---- softmax over j: 16 in-lane values + 2 shuffles (lanes share i) ----
    float m = s[0];
    #pragma unroll
    for (int e = 1; e < 16; ++e) m = fmaxf(m, s[e]);
    m = fmaxf(m, __shfl_xor(m, 16));
    m = fmaxf(m, __shfl_xor(m, 32));
    // p = exp(s-m), in place (s[] dies here -> 16 fewer live VGPRs)
    const float em = __expf(-m);   // sigmoid(s) = p/(p+em); all-masked row -> em=inf -> gate 0
    float sum = 0.f;
    #pragma unroll
    for (int e = 0; e < 16; ++e) { s[e] = __expf(s[e] - m); sum += s[e]; }
    sum += __shfl_xor(sum, 16);
    sum += __shfl_xor(sum, 32);
    const float inv = 1.0f / sum;

    // ---- gate: w = softmax * sigmoid = p*inv * p/(p+em); in-register PV B-frags ----
    bf16x4 wv[4];
    #pragma unroll
    for (int jt = 0; jt < 4; ++jt) {
        #pragma unroll
        for (int r = 0; r < 4; ++r) {
            const float p = s[jt * 4 + r];
            wv[jt][r] = (__bf16)(p * inv * __fdividef(p, p + em));
        }
    }

    // ---- out[d][i] = sum_j V[d][j] * W[i][j], k-slots remapped so the
    //      in-register wv[] IS the B-fragment (no LDS round-trip, no barrier) ----
    f32x4 o0 = {0.f, 0.f, 0.f, 0.f};
    f32x4 o1 = {0.f, 0.f, 0.f, 0.f};
    #pragma unroll
    for (int kt = 0; kt < 2; ++kt) {
        bf16x4 wlo = wv[2 * kt], whi = wv[2 * kt + 1];
        bf16x8 wb = {wlo[0], wlo[1], wlo[2], wlo[3], whi[0], whi[1], whi[2], whi[3]};
        const int c0 = kt * 32 + hi * 4;        // j-block for slots hi*8..+3
        const int c1 = kt * 32 + 16 + hi * 4;   // j-block for slots hi*8+4..+7
        bf16x4 a0l = *(const bf16x4*)&sV[sb][li][c0];
        bf16x4 a0h = *(const bf16x4*)&sV[sb][li][c1];
        bf16x8 va = {a0l[0], a0l[1], a0l[2], a0l[3], a0h[0], a0h[1], a0h[2], a0h[3]};
        bf16x4 a1l = *(const bf16x4*)&sV[sb][16 + li][c0];
        bf16x4 a1h = *(const bf16x4*)&sV[sb][16 + li][c1];
        bf16x8 vc = {a1l[0], a1l[1], a1l[2], a1l[3], a1h[0], a1h[1], a1h[2], a1h[3]};
        o0 = MFMA16(va, wb, o0);
        o1 = MFMA16(vc, wb, o1);
    }
    #pragma unroll
    for (int r = 0; r < 4; ++r) {
        ob[(hi * 4 + r) * 64 + i]      = o0[r];
        ob[(16 + hi * 4 + r) * 64 + i] = o1[r];
    }
}

extern "C" void kernel_launch(void* const* d_in, const int* in_sizes, int n_in,
                              void* d_out, int out_size, void* d_ws, size_t ws_size,
                              hipStream_t stream)
{
    const float* q = (const float*)d_in[0];
    const float* k = (const float*)d_in[1];
    const float* v = (const float*)d_in[2];
    const unsigned char* mask = (const unsigned char*)d_in[3];
    const float* gamma = (const float*)d_in[4];
    const float* bias  = (const float*)d_in[5];
    float* out = (float*)d_out;

    const int num_bh = in_sizes[0] / 2048;   // bs*h = 16384
    dim3 grid(num_bh >> 2), block(1024);     // 4 (b,h) per block
    hipLaunchKernelGGL(mha_fused, grid, block, 0, stream,
                       q, k, v, mask, gamma, bias, out);
}

// Round 4
// 105.090 us; speedup vs baseline: 1.1237x; 1.1237x over previous
//
#include <hip/hip_runtime.h>

typedef __attribute__((ext_vector_type(4))) float  f32x4;
typedef __attribute__((ext_vector_type(2))) float  f32x2;
typedef __attribute__((ext_vector_type(8))) __bf16 bf16x8;
typedef __attribute__((ext_vector_type(4))) __bf16 bf16x4;

#define MFMA16(a, b, c) __builtin_amdgcn_mfma_f32_16x16x32_bf16((a), (b), (c), 0, 0, 0)

// One block per (b,h): bs=2048, h=8, dh=32, qsl=sl=64.
// Design rule: EVERY global access is lane-linear dwordx4 (9 VMEM instrs/wave total);
// all transposes happen in LDS.
__global__ __launch_bounds__(256, 4)
void mha_fused(const float* __restrict__ qg, const float* __restrict__ kg,
               const float* __restrict__ vg, const unsigned char* __restrict__ maskg,
               const float* __restrict__ gammag, const float* __restrict__ biasg,
               float* __restrict__ outg)
{
    const int bh = blockIdx.x;           // natural order: h fast -> mask L2 reuse + streaming
    const int b  = bh >> 3;
    const int h  = bh & 7;
    const int t  = threadIdx.x;

    __shared__ float              sQO[32 * 68];  // A/B: Q raw (stride 66, b32 reads 2-way-free); C/D: out (stride 68, b128-aligned)
    __shared__ float              sKr[32 * 66];  // K raw f32
    __shared__ __bf16             sKh[64][40];   // K^T hi [j][d-slot], 16B-slot XOR swizzle
    __shared__ __bf16             sKl[64][40];   // K^T lo
    __shared__ __bf16             sV [32][72];   // V bf16 [d][j]
    __shared__ unsigned long long sMb[64];       // bitpacked mask rows (bit j of sMb[i])

    const float* qb = qg + (size_t)bh * 2048;
    const float* kb = kg + (size_t)bh * 2048;
    const float* vb = vg + (size_t)bh * 2048;
    const unsigned char* mbp = maskg + (size_t)b * 4096;  // mask broadcast over h
    float* ob = outg + (size_t)bh * 2048;

    const int w  = t >> 6;          // wave id: owns query cols i = w*16..w*16+15
    const int li = t & 15;
    const int hi = (t >> 4) & 3;
    const int i  = w * 16 + li;
    const int rd = t >> 3;          // linear-copy row 0..31
    const int rc = (t & 7) * 8;     // linear-copy col 0,8,..,56

    // ---------------- Phase A: fully-coalesced global -> LDS ----------------
    {
        f32x4 q0 = *(const f32x4*)(qb + t * 8);
        f32x4 q1 = *(const f32x4*)(qb + t * 8 + 4);
        f32x4 k0 = *(const f32x4*)(kb + t * 8);
        f32x4 k1 = *(const f32x4*)(kb + t * 8 + 4);
        f32x4 v0 = *(const f32x4*)(vb + t * 8);
        f32x4 v1 = *(const f32x4*)(vb + t * 8 + 4);
        uint4 mu = *(const uint4*)(mbp + t * 16);

        // q/k raw: 4x ds_write_b64 each (stride 66 keeps transpose-reads 2-way-free;
        // rows are only 8B-aligned so b128 writes are illegal here)
        float* qrow = &sQO[rd * 66 + rc];
        *(f32x2*)(qrow + 0) = (f32x2){q0[0], q0[1]};
        *(f32x2*)(qrow + 2) = (f32x2){q0[2], q0[3]};
        *(f32x2*)(qrow + 4) = (f32x2){q1[0], q1[1]};
        *(f32x2*)(qrow + 6) = (f32x2){q1[2], q1[3]};
        float* krow = &sKr[rd * 66 + rc];
        *(f32x2*)(krow + 0) = (f32x2){k0[0], k0[1]};
        *(f32x2*)(krow + 2) = (f32x2){k0[2], k0[3]};
        *(f32x2*)(krow + 4) = (f32x2){k1[0], k1[1]};
        *(f32x2*)(krow + 6) = (f32x2){k1[2], k1[3]};

        // V: convert once to bf16, natural [d][j]
        bf16x8 vv = {(__bf16)v0[0], (__bf16)v0[1], (__bf16)v0[2], (__bf16)v0[3],
                     (__bf16)v1[0], (__bf16)v1[1], (__bf16)v1[2], (__bf16)v1[3]};
        *(bf16x8*)&sV[rd][rc] = vv;

        // mask: bitpack 16 bytes -> 16 bits (byte order preserved)
        unsigned int n0 = ((mu.x & 0x01010101u) * 0x01020408u) >> 24;
        unsigned int n1 = ((mu.y & 0x01010101u) * 0x01020408u) >> 24;
        unsigned int n2 = ((mu.z & 0x01010101u) * 0x01020408u) >> 24;
        unsigned int n3 = ((mu.w & 0x01010101u) * 0x01020408u) >> 24;
        unsigned int n  = n0 | (n1 << 4) | (n2 << 8) | (n3 << 12);
        ((unsigned short*)sMb)[(t >> 2) * 4 + (t & 3)] = (unsigned short)n;
    }
    __syncthreads();

    // ---------------- Phase B: LDS transposes (no VMEM) ----------------
    // Q fragment: transposed b32 reads + split to hi/lo bf16 (stays in registers)
    bf16x8 qh, ql;
    #pragma unroll
    for (int e = 0; e < 8; ++e) {
        const float a = sQO[(hi * 8 + e) * 66 + i];
        const __bf16 hh = (__bf16)a;
        qh[e] = hh;
        ql[e] = (__bf16)(a - (float)hh);
    }
    // mask row bits for my i (broadcast across the 4 hi-lanes of same i)
    const unsigned long long mrow = sMb[i];
    const unsigned int mlo = (unsigned int)mrow;
    const unsigned int mhw = (unsigned int)(mrow >> 32);

    // K: transposed read + split-convert once, write swizzled frag layout
    {
        const int j = t & 63, sel = t >> 6;
        bf16x8 h8, l8;
        #pragma unroll
        for (int e = 0; e < 8; ++e) {
            const float a = sKr[(sel * 8 + e) * 66 + j];
            const __bf16 hh = (__bf16)a;
            h8[e] = hh;
            l8[e] = (__bf16)(a - (float)hh);
        }
        const int slot = sel ^ ((j >> 3) & 3);
        *(bf16x8*)&sKh[j][slot * 8] = h8;
        *(bf16x8*)&sKl[j][slot * 8] = l8;
    }
    __syncthreads();

    // ---------------- Phase C: QK^T -> softmax*sigmoid -> PV ----------------
    const float ga = gammag[h], be = biasg[h];
    float s[16];
    #pragma unroll
    for (int jt = 0; jt < 4; ++jt) {
        const int j = jt * 16 + li;
        const int slot = hi ^ ((j >> 3) & 3);
        bf16x8 ah = *(bf16x8*)&sKh[j][slot * 8];
        bf16x8 al = *(bf16x8*)&sKl[j][slot * 8];
        f32x4 c = {0.f, 0.f, 0.f, 0.f};
        c = MFMA16(al, qh, c);   // lo*hi
        c = MFMA16(ah, ql, c);   // hi*lo
        c = MFMA16(ah, qh, c);   // hi*hi
        const unsigned int mword = (jt & 2) ? mhw : mlo;
        const unsigned int mnib  = mword >> ((jt & 1) * 16 + hi * 4);
        #pragma unroll
        for (int r = 0; r < 4; ++r) {
            float x = c[r] * ga + be;
            if ((mnib >> r) & 1u) x = -1.0e9f;
            s[jt * 4 + r] = x;
        }
    }

    // softmax over j: 16 in-lane values + 2 shuffles (4 hi-lanes share i)
    float m = s[0];
    #pragma unroll
    for (int e = 1; e < 16; ++e) m = fmaxf(m, s[e]);
    m = fmaxf(m, __shfl_xor(m, 16));
    m = fmaxf(m, __shfl_xor(m, 32));
    const float em = __expf(-m);   // sigmoid(s) = p/(p+em); all-masked -> em=inf -> gate 0
    float sum = 0.f;
    #pragma unroll
    for (int e = 0; e < 16; ++e) { s[e] = __expf(s[e] - m); sum += s[e]; }
    sum += __shfl_xor(sum, 16);
    sum += __shfl_xor(sum, 32);
    const float inv = 1.0f / sum;

    // gate: w = (p*inv) * (p/(p+em)); keep as in-register PV B-fragments
    bf16x4 wv[4];
    #pragma unroll
    for (int jt = 0; jt < 4; ++jt) {
        #pragma unroll
        for (int r = 0; r < 4; ++r) {
            const float p = s[jt * 4 + r];
            wv[jt][r] = (__bf16)(p * inv * __fdividef(p, p + em));
        }
    }

    // PV: out[d][i] = sum_j V[d][j] * W[i][j]; k-slots chosen so wv[] IS the B-frag
    f32x4 o0 = {0.f, 0.f, 0.f, 0.f};
    f32x4 o1 = {0.f, 0.f, 0.f, 0.f};
    #pragma unroll
    for (int kt = 0; kt < 2; ++kt) {
        bf16x4 wlo = wv[2 * kt], whi2 = wv[2 * kt + 1];
        bf16x8 wb = {wlo[0], wlo[1], wlo[2], wlo[3], whi2[0], whi2[1], whi2[2], whi2[3]};
        const int c0 = kt * 32 + hi * 4;
        const int c1 = kt * 32 + 16 + hi * 4;
        bf16x4 a0l = *(const bf16x4*)&sV[li][c0];
        bf16x4 a0h = *(const bf16x4*)&sV[li][c1];
        bf16x8 va = {a0l[0], a0l[1], a0l[2], a0l[3], a0h[0], a0h[1], a0h[2], a0h[3]};
        bf16x4 a1l = *(const bf16x4*)&sV[16 + li][c0];
        bf16x4 a1h = *(const bf16x4*)&sV[16 + li][c1];
        bf16x8 vc = {a1l[0], a1l[1], a1l[2], a1l[3], a1h[0], a1h[1], a1h[2], a1h[3]};
        o0 = MFMA16(va, wb, o0);
        o1 = MFMA16(vc, wb, o1);
    }

    // ---------------- Phase D: out via LDS -> 2 coalesced dwordx4 stores ----------------
    // (barrier #2 already guaranteed all phase-B reads of sQO finished)
    #pragma unroll
    for (int r = 0; r < 4; ++r) {
        sQO[(hi * 4 + r) * 68 + i]      = o0[r];
        sQO[(16 + hi * 4 + r) * 68 + i] = o1[r];
    }
    __syncthreads();
    {
        f32x4 r0 = *(const f32x4*)&sQO[rd * 68 + rc];
        f32x4 r1 = *(const f32x4*)&sQO[rd * 68 + rc + 4];
        *(f32x4*)(ob + t * 8)     = r0;
        *(f32x4*)(ob + t * 8 + 4) = r1;
    }
}

extern "C" void kernel_launch(void* const* d_in, const int* in_sizes, int n_in,
                              void* d_out, int out_size, void* d_ws, size_t ws_size,
                              hipStream_t stream)
{
    const float* q = (const float*)d_in[0];
    const float* k = (const float*)d_in[1];
    const float* v = (const float*)d_in[2];
    const unsigned char* mask = (const unsigned char*)d_in[3];
    const float* gamma = (const float*)d_in[4];
    const float* bias  = (const float*)d_in[5];
    float* out = (float*)d_out;

    const int num_bh = in_sizes[0] / 2048;   // bs*h = 16384
    dim3 grid(num_bh), block(256);
    hipLaunchKernelGGL(mha_fused, grid, block, 0, stream,
                       q, k, v, mask, gamma, bias, out);
}